// Round 1
// 369.590 us; speedup vs baseline: 1.0318x; 1.0318x over previous
//
#include <hip/hip_runtime.h>
#include <hip/hip_bf16.h>
#include <math.h>

#define V     8000
#define D_    300
#define B_    128
#define L_    300
#define C_    54
#define CHUNK 12            // 300 = 25 * 12 ; one float4-triplet per l
#define NCH   25
#define NU    (L_ * 3)      // 900 float4 units per block
#define WSTR  9             // padded w stride (spread broadcast banks)

// ---------------- Kernel 1: gather edge weights + eta ----------------
// one thread per (b,l,o) -> max TLP for the random edges_matrix gather
// w_ws layout: [B][L][8] (o padded 7->8); eta_ws: [B][L]
__global__ __launch_bounds__(256) void wgather_kernel(
    const float* __restrict__ edge_w,
    const float* __restrict__ node_eta,
    const int*   __restrict__ docs,
    const int*   __restrict__ edges_matrix,
    float* __restrict__ w_ws,
    float* __restrict__ eta_ws)
{
    int idx = blockIdx.x * 256 + threadIdx.x;
    if (idx >= B_ * L_ * 7) return;
    int b   = idx / (L_ * 7);
    int rem = idx - b * (L_ * 7);
    int l   = rem / 7;
    int o   = rem - l * 7;
    const int* drow = docs + b * L_;
    int d1 = drow[l];
    int nb = min(max(l + o - 3, 0), L_ - 1);
    int d2 = drow[nb];
    int eid = edges_matrix[(size_t)d1 * V + d2];
    w_ws[((size_t)b * L_ + l) * 8 + o] = edge_w[eid];
    if (o == 3) eta_ws[b * L_ + l] = node_eta[d1];
}

// ---------------- Kernel 2: h0 gather + T=2 propagation + pooled sum ----------------
// grid: (25, B), block: 256. float4 over the d-axis:
//   unit e = 3*l + dv  (dv in [0,3), 4 floats each)  -> h4[e] is the float4
//   neighbor (l+o-3, dv) is h4[e + (o-3)*3]  -> ds_read_b128, contiguous lanes
//   w/eta broadcast reads amortized over 4 d-values
__global__ __launch_bounds__(256, 4) void prop_kernel(
    const float* __restrict__ node_embed,
    const float* __restrict__ eta_ws,
    const float* __restrict__ w_ws,
    const int*   __restrict__ docs,
    float* __restrict__ pooled)   // [B][D]
{
    int b   = blockIdx.y;
    int bx  = blockIdx.x;          // d0 = bx * 12
    int tid = threadIdx.x;

    __shared__ __align__(16) float h_s[L_ * CHUNK];   // 14400 B
    __shared__ float w_s[L_ * WSTR];                  // 10800 B
    __shared__ float eta_s[L_];                       //  1200 B
    __shared__ int   docs_s[L_];                      //  1200 B
    __shared__ __align__(16) float red[150 * 4];      //  2400 B  -> ~30 KB => 5 blocks/CU

    float4* h4   = reinterpret_cast<float4*>(h_s);
    float4* red4 = reinterpret_cast<float4*>(red);

    for (int l = tid; l < L_; l += 256) {
        docs_s[l] = docs[b * L_ + l];
        eta_s[l]  = eta_ws[b * L_ + l];
    }
    for (int i = tid; i < L_ * 8; i += 256) {
        int l = i >> 3, o = i & 7;
        w_s[l * WSTR + o] = w_ws[(size_t)b * (L_ * 8) + i];
    }
    __syncthreads();

    // h0 gather: one float4 per unit (16B aligned: 300*doc + 12*bx + 4*dv)
    const float4* ne4 = reinterpret_cast<const float4*>(node_embed);
    #pragma unroll
    for (int k = 0; k < 4; ++k) {
        int e = tid + k * 256;
        if (e < NU) {
            int l  = e / 3;
            int dv = e - l * 3;
            h4[e] = ne4[(size_t)docs_s[l] * (D_ / 4) + bx * 3 + dv];
        }
    }
    __syncthreads();

    for (int step = 0; step < 2; ++step) {
        float4 nv[4];
        #pragma unroll
        for (int k = 0; k < 4; ++k) {
            int e = tid + k * 256;
            if (e < NU) {
                int l = e / 3;
                float4 own = h4[e];
                float4 msg = make_float4(-3.402823466e38f, -3.402823466e38f,
                                         -3.402823466e38f, -3.402823466e38f);
                const float* wl = &w_s[l * WSTR];
                #pragma unroll
                for (int o = 0; o < 7; ++o) {
                    int nb = l + o - 3;
                    if ((unsigned)nb < (unsigned)L_) {
                        float  wv = wl[o];
                        float4 hv = (o == 3) ? own : h4[e + (o - 3) * 3];
                        msg.x = fmaxf(msg.x, wv * hv.x);
                        msg.y = fmaxf(msg.y, wv * hv.y);
                        msg.z = fmaxf(msg.z, wv * hv.z);
                        msg.w = fmaxf(msg.w, wv * hv.w);
                    }
                }
                float et = eta_s[l];
                float om = 1.f - et;
                nv[k].x = et * own.x + om * msg.x;
                nv[k].y = et * own.y + om * msg.y;
                nv[k].z = et * own.z + om * msg.z;
                nv[k].w = et * own.w + om * msg.w;
            }
        }
        __syncthreads();
        #pragma unroll
        for (int k = 0; k < 4; ++k) {
            int e = tid + k * 256;
            if (e < NU) h4[e] = nv[k];
        }
        __syncthreads();
    }

    // pooled[b, d0 + dv*4 + j] = sum_l h ; two-stage float4 reduction
    if (tid < 150) {
        int grp = tid / 3;            // 0..49
        int dv  = tid - grp * 3;
        float4 s = make_float4(0.f, 0.f, 0.f, 0.f);
        #pragma unroll
        for (int j = 0; j < 6; ++j) {
            float4 v = h4[(grp + j * 50) * 3 + dv];
            s.x += v.x; s.y += v.y; s.z += v.z; s.w += v.w;
        }
        red4[tid] = s;
    }
    __syncthreads();
    if (tid < 3) {
        float4 s = make_float4(0.f, 0.f, 0.f, 0.f);
        for (int g = 0; g < 50; ++g) {
            float4 v = red4[g * 3 + tid];
            s.x += v.x; s.y += v.y; s.z += v.z; s.w += v.w;
        }
        reinterpret_cast<float4*>(pooled)[(size_t)b * (D_ / 4) + bx * 3 + tid] = s;
    }
}

// ---------------- Kernel 3: relu + batchnorm over batch axis ----------------
__global__ __launch_bounds__(128) void bn_kernel(
    const float* __restrict__ pooled,
    const float* __restrict__ gamma,
    const float* __restrict__ beta,
    float* __restrict__ xn)
{
    int d = blockIdx.x;
    int b = threadIdx.x;
    float x = fmaxf(pooled[b * D_ + d], 0.f);

    float v1 = x, v2 = x * x;
    #pragma unroll
    for (int off = 32; off > 0; off >>= 1) {
        v1 += __shfl_down(v1, off, 64);
        v2 += __shfl_down(v2, off, 64);
    }
    __shared__ float s1[2], s2[2];
    int lane = b & 63, wv = b >> 6;
    if (lane == 0) { s1[wv] = v1; s2[wv] = v2; }
    __syncthreads();
    float mean = (s1[0] + s1[1]) * (1.f / 128.f);
    float var  = (s2[0] + s2[1]) * (1.f / 128.f) - mean * mean;
    float xh = (x - mean) / sqrtf(var + 1e-5f);
    xn[b * D_ + d] = xh * gamma[d] + beta[d];
}

// ---------------- Kernel 4: matmul + bias + sigmoid ----------------
__global__ __launch_bounds__(64) void out_kernel(
    const float* __restrict__ xn,
    const float* __restrict__ Wm,
    const float* __restrict__ bias,
    float* __restrict__ out)
{
    int b = blockIdx.x;
    int c = threadIdx.x;
    if (c >= C_) return;
    float acc = bias[c];
    for (int k = 0; k < D_; ++k)
        acc = fmaf(xn[b * D_ + k], Wm[k * C_ + c], acc);
    out[b * C_ + c] = 1.f / (1.f + expf(-acc));
}

extern "C" void kernel_launch(void* const* d_in, const int* in_sizes, int n_in,
                              void* d_out, int out_size, void* d_ws, size_t ws_size,
                              hipStream_t stream) {
    const float* node_embed   = (const float*)d_in[0];
    const float* node_eta     = (const float*)d_in[1];
    const float* edge_w       = (const float*)d_in[2];
    const float* bn_gamma     = (const float*)d_in[3];
    const float* bn_beta      = (const float*)d_in[4];
    const float* Wm           = (const float*)d_in[5];
    const float* bias         = (const float*)d_in[6];
    const int*   docs         = (const int*)d_in[7];
    const int*   edges_matrix = (const int*)d_in[8];
    float* out = (float*)d_out;

    // workspace layout
    float* w_ws   = (float*)d_ws;                       // B*L*8
    float* eta_ws = w_ws + (size_t)B_ * L_ * 8;         // B*L
    float* pooled = eta_ws + (size_t)B_ * L_;           // B*D
    float* xn     = pooled + (size_t)B_ * D_;           // B*D

    // 1. edge-weight + eta gather (one thread per edge: max TLP)
    {
        int total = B_ * L_ * 7;
        wgather_kernel<<<(total + 255) / 256, 256, 0, stream>>>(
            edge_w, node_eta, docs, edges_matrix, w_ws, eta_ws);
    }
    // 2. propagation (float4 over d)
    {
        dim3 grid(NCH, B_);  // (25, 128)
        prop_kernel<<<grid, 256, 0, stream>>>(node_embed, eta_ws, w_ws, docs, pooled);
    }
    // 3. batchnorm
    bn_kernel<<<D_, 128, 0, stream>>>(pooled, bn_gamma, bn_beta, xn);
    // 4. output
    out_kernel<<<B_, 64, 0, stream>>>(xn, Wm, bias, out);
}